// Round 1
// 418.329 us; speedup vs baseline: 1.0265x; 1.0265x over previous
//
#include <hip/hip_runtime.h>

// Problem constants (fixed by the reference setup_inputs).
constexpr int kB = 4, kT = 4096, kN = 4, kC = 1024;
constexpr int kChunks = kC / 4;              // float4 chunks per (b,t,n) row = 256
constexpr int kHalf   = kChunks / 2;         // 128: each thread covers c4 and c4+128
constexpr int kThreads = kB * kT * kHalf;    // 2,097,152 threads

// Native vector type so __builtin_nontemporal_{load,store} accept it.
typedef float v4f __attribute__((ext_vector_type(4)));

__global__ __launch_bounds__(256) void hyperconn_kernel(
    const v4f* __restrict__ x4,
    const float* __restrict__ pre_w,     // (n,)
    const float* __restrict__ post_w,    // (n,)
    const float* __restrict__ res_w,     // (n,n) row-major, res_w[m*kN+n]
    v4f* __restrict__ out4)
{
    // ---- softmax of the tiny weight vectors, fp32, wave-uniform ----
    float pw[kN], qw[kN], rw[kN][kN];
    float pmax = -1e30f, qmax = -1e30f;
#pragma unroll
    for (int i = 0; i < kN; ++i) {
        pw[i] = pre_w[i];
        qw[i] = post_w[i];
        pmax = fmaxf(pmax, pw[i]);
        qmax = fmaxf(qmax, qw[i]);
    }
    float ps = 0.f, qs = 0.f;
#pragma unroll
    for (int i = 0; i < kN; ++i) {
        pw[i] = __expf(pw[i] - pmax); ps += pw[i];
        qw[i] = __expf(qw[i] - qmax); qs += qw[i];
    }
    const float pinv = 1.f / ps, qinv = 1.f / qs;
#pragma unroll
    for (int i = 0; i < kN; ++i) { pw[i] *= pinv; qw[i] *= qinv; }
#pragma unroll
    for (int m = 0; m < kN; ++m)
#pragma unroll
        for (int n = 0; n < kN; ++n)
            rw[m][n] = res_w[m * kN + n];

    // ---- per-thread position: (bt, c4) with c4 in [0,128); handles c4 and c4+128 ----
    const int tid = blockIdx.x * blockDim.x + threadIdx.x;     // < 2^21
    const int c4  = tid & (kHalf - 1);
    const int bt  = tid >> 7;                                   // kHalf = 128
    const int base = bt * (kN * kChunks) + c4;                  // float4 index of (bt, n=0, c4)

    // 8 coalesced 16B nontemporal loads (each instruction = contiguous 1KB per wave).
    v4f xv[kN][2];
#pragma unroll
    for (int n = 0; n < kN; ++n) {
#pragma unroll
        for (int hh = 0; hh < 2; ++hh)
            xv[n][hh] = __builtin_nontemporal_load(&x4[base + n * kChunks + hh * kHalf]);
    }

#pragma unroll
    for (int hh = 0; hh < 2; ++hh) {
        // h[j] = sum_n pw[n] * x[n][j]   (same per-element fma ordering as before)
        v4f h = xv[0][hh] * pw[0];
#pragma unroll
        for (int n = 1; n < kN; ++n) h += xv[n][hh] * pw[n];

        // out[m][j] = qw[m]*h[j] + sum_n rw[m][n]*x[n][j]
#pragma unroll
        for (int m = 0; m < kN; ++m) {
            v4f o = h * qw[m];
#pragma unroll
            for (int n = 0; n < kN; ++n) o += xv[n][hh] * rw[m][n];
            __builtin_nontemporal_store(o, &out4[base + m * kChunks + hh * kHalf]);
        }
    }
}

extern "C" void kernel_launch(void* const* d_in, const int* in_sizes, int n_in,
                              void* d_out, int out_size, void* d_ws, size_t ws_size,
                              hipStream_t stream) {
    const v4f* x4 = (const v4f*)d_in[0];
    const float* pre_w  = (const float*)d_in[1];
    const float* post_w = (const float*)d_in[2];
    const float* res_w  = (const float*)d_in[3];
    v4f* out4 = (v4f*)d_out;

    const int block = 256;
    const int grid = kThreads / block;   // 8192 blocks
    hipLaunchKernelGGL(hyperconn_kernel, dim3(grid), dim3(block), 0, stream,
                       x4, pre_w, post_w, res_w, out4);
}